// Round 7
// baseline (57.895 us; speedup 1.0000x reference)
//
#include <hip/hip_runtime.h>
#include <hip/hip_bf16.h>
#include <math.h>

// R7: store-pattern ablation + LDS-repacked coalesced-store kernel.
//   dispatch 1: prep_wfrag
//   dispatch 2: abl_store  -- compute + EXACT strided-store epilogue (64B
//               segments @ 256KB stride) to d_out, staging reg-filled.
//               Isolates the store-channel-conflict theory.
//   dispatch 3: dconv_fused3 -- real kernel: R6 staging + compute, epilogue
//               repacked through LDS -> dwordx4 contiguous stores.
//               (d_out garbage from abl_store is fully overwritten here.)

#define ALPHA_F 8.3f

constexpr int B_    = 4;
constexpr int CIN   = 32;
constexpr int COUT  = 32;
constexpr int H_    = 256;
constexpr int W_    = 256;
constexpr int KTAPS = 9;
constexpr int HW    = H_ * W_;

typedef __attribute__((ext_vector_type(8))) short bf16x8;
typedef __attribute__((ext_vector_type(4))) float f32x4;

static __device__ __forceinline__ short f2bf(float f) {
    __hip_bfloat16 h = __float2bfloat16(f);
    return __builtin_bit_cast(short, h);
}

// ---- prep: weights into per-lane A-fragment layout (verified R2-R6) ----
__global__ void prep_wfrag(const float* __restrict__ w, short* __restrict__ wf) {
    int idx = blockIdx.x * 256 + threadIdx.x;
    if (idx >= KTAPS * 2 * 64 * 8) return;
    int e  = idx & 7;
    int l  = (idx >> 3) & 63;
    int t  = (idx >> 9) & 1;
    int ij = idx >> 10;
    int o  = t * 16 + (l & 15);
    int c  = (l >> 4) * 8 + e;
    wf[idx] = f2bf(w[(o * CIN + c) * KTAPS + ij]);
}

// ---- ABLATION: compute + strided stores (staging reg-filled) ----
__global__ __launch_bounds__(256)
void abl_store(const short* __restrict__ wf, float* __restrict__ out) {
    __shared__ __align__(16) short xs[3][130][40];
    __shared__ float dsh[3][130];

    const int bid  = (int)blockIdx.x;
    const int bswz = (bid & 7) * 256 + (bid >> 3);
    const int b    = bswz >> 9;
    const int h    = (bswz >> 1) & 255;
    const int wseg = (bswz & 1) << 7;
    const int tid  = threadIdx.x;

    // cheap reg->LDS fill (no global loads)
    {
        ushort4* xsv = (ushort4*)&xs[0][0][0];   // 15600/4 = 3900 chunks
#pragma unroll
        for (int it = 0; it < 16; ++it) {
            const int idx = it * 256 + tid;
            if (idx < 3900) {
                const unsigned short a = (unsigned short)f2bf((float)(idx & 63) * 0.01f);
                const unsigned short c = (unsigned short)f2bf((float)((idx >> 3) & 63) * 0.02f);
                ushort4 v; v.x = a; v.y = c; v.z = a; v.w = c;
                xsv[idx] = v;
            }
        }
        for (int k = tid; k < 390; k += 256) {
            const int r = k / 130, q = k - r * 130;
            dsh[r][q] = (float)q * 0.003f + (float)r * 0.01f;
        }
    }
    __syncthreads();

    const int lane = tid & 63;
    const int warp = tid >> 6;
    const int n    = lane & 15;
    const int cg   = (lane >> 4) * 8;
    const int pl0  = warp * 32 + n + 1;
    const int pl1  = pl0 + 16;
    const int wp0  = wseg + warp * 32 + n;
    const int wp1  = wp0 + 16;

    const float dc0 = dsh[1][pl0];
    const float dc1 = dsh[1][pl1];

    float s0[KTAPS], s1[KTAPS];
#pragma unroll
    for (int ij = 0; ij < KTAPS; ++ij) {
        const int di = ij / 3 - 1;
        const int dj = ij % 3 - 1;
        const bool okh = ((unsigned)(h + di) < (unsigned)H_);
        const bool ok0 = okh && ((unsigned)(wp0 + dj) < (unsigned)W_);
        const bool ok1 = okh && ((unsigned)(wp1 + dj) < (unsigned)W_);
        s0[ij] = ok0 ? __expf(-ALPHA_F * fabsf(dc0 - dsh[1 + di][pl0 + dj])) : 0.f;
        s1[ij] = ok1 ? __expf(-ALPHA_F * fabsf(dc1 - dsh[1 + di][pl1 + dj])) : 0.f;
    }

    const bf16x8* wfv = (const bf16x8*)wf;
    f32x4 a00 = {0.f,0.f,0.f,0.f}, a01 = {0.f,0.f,0.f,0.f};
    f32x4 a10 = {0.f,0.f,0.f,0.f}, a11 = {0.f,0.f,0.f,0.f};
    const f32x4 z = {0.f, 0.f, 0.f, 0.f};
#pragma unroll
    for (int ij = 0; ij < KTAPS; ++ij) {
        const int di = ij / 3 - 1;
        const int dj = ij % 3 - 1;
        const bf16x8 wa0 = wfv[(ij * 2 + 0) * 64 + lane];
        const bf16x8 wa1 = wfv[(ij * 2 + 1) * 64 + lane];
        const bf16x8 b0  = *(const bf16x8*)&xs[1 + di][pl0 + dj][cg];
        const bf16x8 b1  = *(const bf16x8*)&xs[1 + di][pl1 + dj][cg];
        const f32x4 t0 = __builtin_amdgcn_mfma_f32_16x16x32_bf16(wa0, b0, z, 0, 0, 0);
        const f32x4 t1 = __builtin_amdgcn_mfma_f32_16x16x32_bf16(wa1, b0, z, 0, 0, 0);
        const f32x4 t2 = __builtin_amdgcn_mfma_f32_16x16x32_bf16(wa0, b1, z, 0, 0, 0);
        const f32x4 t3 = __builtin_amdgcn_mfma_f32_16x16x32_bf16(wa1, b1, z, 0, 0, 0);
#pragma unroll
        for (int j = 0; j < 4; ++j) {
            a00[j] = fmaf(s0[ij], t0[j], a00[j]);
            a01[j] = fmaf(s0[ij], t1[j], a01[j]);
            a10[j] = fmaf(s1[ij], t2[j], a10[j]);
            a11[j] = fmaf(s1[ij], t3[j], a11[j]);
        }
    }

    // EXACT strided epilogue of R6 (the suspect): 64B segments @ 256KB stride
    const int orow = (lane >> 4) * 4;
    float* ob0 = out + (size_t)b * COUT * HW + h * W_ + wp0;
    float* ob1 = out + (size_t)b * COUT * HW + h * W_ + wp1;
#pragma unroll
    for (int j = 0; j < 4; ++j) {
        ob0[(orow + j) * HW]      = a00[j];
        ob0[(orow + j + 16) * HW] = a01[j];
        ob1[(orow + j) * HW]      = a10[j];
        ob1[(orow + j + 16) * HW] = a11[j];
    }
}

// ---- real kernel: R6 staging + compute, LDS-repacked coalesced stores ----
__global__ __launch_bounds__(256)
void dconv_fused3(const float* __restrict__ x,
                  const float* __restrict__ depth,
                  const short* __restrict__ wf,
                  float* __restrict__ out) {
    __shared__ __align__(16) short xs[3][130][40];   // 31200 B; reused as accbuf
    __shared__ float dsh[3][130];                    //  1560 B

    const int bid  = (int)blockIdx.x;
    const int bswz = (bid & 7) * 256 + (bid >> 3);
    const int b    = bswz >> 9;
    const int h    = (bswz >> 1) & 255;
    const int wseg = (bswz & 1) << 7;
    const int tid  = threadIdx.x;
    const float* xb  = x + (size_t)b * CIN * HW;
    const float* dpl = depth + (size_t)b * HW;

    // ---- stage (R6): channel-pair b32 writes ----
#pragma unroll
    for (int it = 0; it < 24; ++it) {
        const int idx = it * 256 + tid;
        const int q   = idx & 127;
        const int rc  = idx >> 7;
        const int cp  = rc & 15;
        const int r   = rc >> 4;
        const int row = h + r - 1;
        const bool ok = ((unsigned)row < (unsigned)H_);
        const size_t gb = (size_t)(2 * cp) * HW + row * W_ + wseg + q;
        const float f0 = ok ? xb[gb]      : 0.f;
        const float f1 = ok ? xb[gb + HW] : 0.f;
        const int v = (int)(unsigned short)f2bf(f0) |
                      ((int)(unsigned short)f2bf(f1) << 16);
        ((int*)&xs[r][q + 1][0])[cp] = v;
    }
    if (tid < 96) {
        const int side = tid & 1;
        const int rc   = tid >> 1;
        const int cp   = rc & 15;
        const int r    = rc >> 4;
        const int row  = h + r - 1;
        const int wx   = wseg - 1 + side * 129;
        const int ql   = side * 129;
        const bool ok  = ((unsigned)row < (unsigned)H_) &&
                         ((unsigned)wx  < (unsigned)W_);
        const size_t gb = (size_t)(2 * cp) * HW + row * W_ + wx;
        const float f0 = ok ? xb[gb]      : 0.f;
        const float f1 = ok ? xb[gb + HW] : 0.f;
        const int v = (int)(unsigned short)f2bf(f0) |
                      ((int)(unsigned short)f2bf(f1) << 16);
        ((int*)&xs[r][ql][0])[cp] = v;
    }
    for (int k = tid; k < 390; k += 256) {
        const int r   = k / 130;
        const int q   = k - r * 130;
        const int row = h + r - 1;
        const int wx  = wseg - 1 + q;
        const bool ok = ((unsigned)row < (unsigned)H_) &&
                        ((unsigned)wx  < (unsigned)W_);
        dsh[r][q] = ok ? dpl[row * W_ + wx] : 0.f;
    }
    __syncthreads();

    // ---- compute (R6): 2 subtiles per wave ----
    const int lane = tid & 63;
    const int warp = tid >> 6;
    const int n    = lane & 15;
    const int cg   = (lane >> 4) * 8;
    const int pl0  = warp * 32 + n + 1;
    const int pl1  = pl0 + 16;
    const int wp0  = wseg + warp * 32 + n;
    const int wp1  = wp0 + 16;

    const float dc0 = dsh[1][pl0];
    const float dc1 = dsh[1][pl1];

    float s0[KTAPS], s1[KTAPS];
#pragma unroll
    for (int ij = 0; ij < KTAPS; ++ij) {
        const int di = ij / 3 - 1;
        const int dj = ij % 3 - 1;
        const bool okh = ((unsigned)(h + di) < (unsigned)H_);
        const bool ok0 = okh && ((unsigned)(wp0 + dj) < (unsigned)W_);
        const bool ok1 = okh && ((unsigned)(wp1 + dj) < (unsigned)W_);
        s0[ij] = ok0 ? __expf(-ALPHA_F * fabsf(dc0 - dsh[1 + di][pl0 + dj])) : 0.f;
        s1[ij] = ok1 ? __expf(-ALPHA_F * fabsf(dc1 - dsh[1 + di][pl1 + dj])) : 0.f;
    }

    const bf16x8* wfv = (const bf16x8*)wf;
    f32x4 a00 = {0.f,0.f,0.f,0.f}, a01 = {0.f,0.f,0.f,0.f};
    f32x4 a10 = {0.f,0.f,0.f,0.f}, a11 = {0.f,0.f,0.f,0.f};
    const f32x4 z = {0.f, 0.f, 0.f, 0.f};
#pragma unroll
    for (int ij = 0; ij < KTAPS; ++ij) {
        const int di = ij / 3 - 1;
        const int dj = ij % 3 - 1;
        const bf16x8 wa0 = wfv[(ij * 2 + 0) * 64 + lane];
        const bf16x8 wa1 = wfv[(ij * 2 + 1) * 64 + lane];
        const bf16x8 b0  = *(const bf16x8*)&xs[1 + di][pl0 + dj][cg];
        const bf16x8 b1  = *(const bf16x8*)&xs[1 + di][pl1 + dj][cg];
        const f32x4 t0 = __builtin_amdgcn_mfma_f32_16x16x32_bf16(wa0, b0, z, 0, 0, 0);
        const f32x4 t1 = __builtin_amdgcn_mfma_f32_16x16x32_bf16(wa1, b0, z, 0, 0, 0);
        const f32x4 t2 = __builtin_amdgcn_mfma_f32_16x16x32_bf16(wa0, b1, z, 0, 0, 0);
        const f32x4 t3 = __builtin_amdgcn_mfma_f32_16x16x32_bf16(wa1, b1, z, 0, 0, 0);
#pragma unroll
        for (int j = 0; j < 4; ++j) {
            a00[j] = fmaf(s0[ij], t0[j], a00[j]);
            a01[j] = fmaf(s0[ij], t1[j], a01[j]);
            a10[j] = fmaf(s1[ij], t2[j], a10[j]);
            a11[j] = fmaf(s1[ij], t3[j], a11[j]);
        }
    }

    // ---- epilogue: repack via LDS (alias dead xs), coalesced dwordx4 stores ----
    __syncthreads();                      // all xs reads done
    float* accbuf = (float*)&xs[0][0][0]; // [32][136] f32 = 17408 B <= 31200 B
    const int orow = (lane >> 4) * 4;
    const int px0  = warp * 32 + n;
#pragma unroll
    for (int j = 0; j < 4; ++j) {
        accbuf[(orow + j) * 136 + px0]           = a00[j];
        accbuf[(orow + j + 16) * 136 + px0]      = a01[j];
        accbuf[(orow + j) * 136 + px0 + 16]      = a10[j];
        accbuf[(orow + j + 16) * 136 + px0 + 16] = a11[j];
    }
    __syncthreads();

    float* ob = out + (size_t)b * COUT * HW + h * W_ + wseg;
    const int px4 = (tid & 31) * 4;       // 4 consecutive px per thread
#pragma unroll
    for (int k = 0; k < 4; ++k) {
        const int ch = k * 8 + (tid >> 5);
        const f32x4 v = *(const f32x4*)&accbuf[ch * 136 + px4];
        *(f32x4*)(ob + (size_t)ch * HW + px4) = v;  // 512B contiguous per 32 lanes
    }
}

// ---------- fp32 fallback (R1 kernel) ----------
__global__ __launch_bounds__(256)
void dconv_fallback(const float* __restrict__ x,
                    const float* __restrict__ depth,
                    const float* __restrict__ wgt,
                    float* __restrict__ out) {
    const int w  = threadIdx.x;
    const int bh = blockIdx.x;
    const int b  = bh >> 8;
    const int h  = bh & 255;

    const float* dplane = depth + (size_t)b * HW;
    const float  dc     = dplane[h * W_ + w];

    float acc[COUT];
#pragma unroll
    for (int o = 0; o < COUT; ++o) acc[o] = 0.f;

    const float* xb = x + (size_t)b * CIN * HW;

    for (int i = 0; i < 3; ++i) {
        const int  hh  = h + i - 1;
        const bool okh = ((unsigned)hh < (unsigned)H_);
        for (int j = 0; j < 3; ++j) {
            const int  ww = w + j - 1;
            const bool ok = okh && ((unsigned)ww < (unsigned)W_);
            const int  ij = i * 3 + j;
            const float dpv = ok ? dplane[hh * W_ + ww] : 0.f;
            const float sv  = __expf(-ALPHA_F * fabsf(dc - dpv));
            const int base = hh * W_ + ww;
#pragma unroll
            for (int c = 0; c < CIN; ++c) {
                const float v = (ok ? xb[c * HW + base] : 0.f) * sv;
#pragma unroll
                for (int o = 0; o < COUT; ++o) {
                    acc[o] = fmaf(v, wgt[(o * CIN + c) * KTAPS + ij], acc[o]);
                }
            }
        }
    }

    float* ob = out + ((size_t)b * COUT * H_ + h) * W_ + w;
#pragma unroll
    for (int o = 0; o < COUT; ++o) ob[o * HW] = acc[o];
}

extern "C" void kernel_launch(void* const* d_in, const int* in_sizes, int n_in,
                              void* d_out, int out_size, void* d_ws, size_t ws_size,
                              hipStream_t stream) {
    const float* x     = (const float*)d_in[0];
    const float* depth = (const float*)d_in[1];
    const float* wgt   = (const float*)d_in[2];
    float*       out   = (float*)d_out;

    const size_t wf_bytes = (size_t)(KTAPS * 2 * 64 * 8) * sizeof(short); // 18 KB

    if (ws_size >= wf_bytes) {
        short* wf = (short*)d_ws;
        prep_wfrag<<<(KTAPS * 2 * 64 * 8 + 255) / 256, 256, 0, stream>>>(wgt, wf);
        // ablation writes strided garbage to d_out; dconv_fused3 then
        // overwrites every element of d_out (full coverage) -> deterministic.
        abl_store<<<2048, 256, 0, stream>>>(wf, out);
        dconv_fused3<<<2048, 256, 0, stream>>>(x, depth, wf, out);
    } else {
        dconv_fallback<<<B_ * H_, 256, 0, stream>>>(x, depth, wgt, out);
    }
}

// Round 8
// 27.105 us; speedup vs baseline: 2.1359x; 2.1359x over previous
//
#include <hip/hip_runtime.h>
#include <hip/hip_bf16.h>
#include <math.h>

// R8: fused kernel with fully-batched staging.
// R6/R7 ablations: compute ~5us, strided stores ~free, staging ~45us.
// Cause: VGPR-starved codegen serialized staging into per-pair
// load->waitcnt->cvt->ds_write (24 exposed latencies/wave).
// Fix: phase A issues ALL 52 global loads into registers (no intervening
// uses -> single pipelined vmcnt drain), phase B converts+writes to LDS.
// launch_bounds(256,3) gives the allocator room (no spill, ~170 cap).
// Epilogue: strided stores (proven fast in R7 ablation), nontemporal so
// the out-stream stops evicting x from L3.

#define ALPHA_F 8.3f

constexpr int B_    = 4;
constexpr int CIN   = 32;
constexpr int COUT  = 32;
constexpr int H_    = 256;
constexpr int W_    = 256;
constexpr int KTAPS = 9;
constexpr int HW    = H_ * W_;

typedef __attribute__((ext_vector_type(8))) short bf16x8;
typedef __attribute__((ext_vector_type(4))) float f32x4;

static __device__ __forceinline__ short f2bf(float f) {
    __hip_bfloat16 h = __float2bfloat16(f);
    return __builtin_bit_cast(short, h);
}

// ---- prep: weights into per-lane A-fragment layout (verified R2-R7) ----
__global__ void prep_wfrag(const float* __restrict__ w, short* __restrict__ wf) {
    int idx = blockIdx.x * 256 + threadIdx.x;
    if (idx >= KTAPS * 2 * 64 * 8) return;
    int e  = idx & 7;
    int l  = (idx >> 3) & 63;
    int t  = (idx >> 9) & 1;
    int ij = idx >> 10;
    int o  = t * 16 + (l & 15);
    int c  = (l >> 4) * 8 + e;
    wf[idx] = f2bf(w[(o * CIN + c) * KTAPS + ij]);
}

// ---- fused main kernel ----
__global__ __launch_bounds__(256, 3)
void dconv_fused4(const float* __restrict__ x,
                  const float* __restrict__ depth,
                  const short* __restrict__ wf,
                  float* __restrict__ out) {
    __shared__ __align__(16) short xs[3][130][40];   // 31200 B bf16 x tile
    __shared__ float dsh[3][130];                    //  1560 B depth stencil

    const int bid  = (int)blockIdx.x;
    const int bswz = (bid & 7) * 256 + (bid >> 3);   // XCD-bijective swizzle
    const int b    = bswz >> 9;
    const int h    = (bswz >> 1) & 255;
    const int wseg = (bswz & 1) << 7;                // 128-px segment base
    const int tid  = threadIdx.x;
    const float* xb  = x + (size_t)b * CIN * HW;
    const float* dpl = depth + (size_t)b * HW;

    // ================= PHASE A: issue ALL global loads =================
    // x main tile: 24 channel-pair loads (clamped addresses, select later)
    float xv0[24], xv1[24];
#pragma unroll
    for (int it = 0; it < 24; ++it) {
        const int idx = it * 256 + tid;
        const int q   = idx & 127;
        const int rc  = idx >> 7;
        const int cp  = rc & 15;
        const int r   = rc >> 4;
        const int row = h + r - 1;
        const int rowc = ((unsigned)row < (unsigned)H_) ? row : h;  // clamp
        const size_t gb = (size_t)(2 * cp) * HW + rowc * W_ + wseg + q;
        xv0[it] = xb[gb];
        xv1[it] = xb[gb + HW];
    }
    // halo columns: 2 edge px x 3 rows x 16 ch-pairs (threads 0..95 active)
    float hv0, hv1;
    {
        const int side = tid & 1;
        const int hrc  = tid >> 1;
        const int hcp  = hrc & 15;
        const int hr   = (hrc >> 4) % 3;
        const int hrow = h + hr - 1;
        const int hwx  = wseg - 1 + side * 129;
        const bool hok = (tid < 96) &&
                         ((unsigned)hrow < (unsigned)H_) &&
                         ((unsigned)hwx  < (unsigned)W_);
        const size_t gb = (size_t)(2 * hcp) * HW +
                          (hok ? (size_t)(hrow * W_ + hwx) : 0);
        hv0 = xb[gb];
        hv1 = xb[gb + HW];
    }
    // depth stencil: 3 x 130 = 390 values (k = tid, tid+256)
    float dv0, dv1;
    {
        const int r0   = tid / 130;
        const int q0   = tid - r0 * 130;
        const int row0 = h + r0 - 1;
        const int wx0  = wseg - 1 + q0;
        const bool ok0 = ((unsigned)row0 < (unsigned)H_) &&
                         ((unsigned)wx0  < (unsigned)W_);
        dv0 = dpl[ok0 ? (row0 * W_ + wx0) : 0];

        const int k1   = tid + 256;
        const int r1   = k1 / 130;
        const int q1   = k1 - r1 * 130;
        const int row1 = h + (r1 % 3) - 1;
        const int wx1  = wseg - 1 + q1;
        const bool ok1 = (k1 < 390) &&
                         ((unsigned)row1 < (unsigned)H_) &&
                         ((unsigned)wx1  < (unsigned)W_);
        dv1 = dpl[ok1 ? (row1 * W_ + wx1) : 0];
    }

    // ================= PHASE B: convert + LDS writes =================
#pragma unroll
    for (int it = 0; it < 24; ++it) {
        const int idx = it * 256 + tid;
        const int q   = idx & 127;
        const int rc  = idx >> 7;
        const int cp  = rc & 15;
        const int r   = rc >> 4;
        const bool ok = ((unsigned)(h + r - 1) < (unsigned)H_);
        const float f0 = ok ? xv0[it] : 0.f;
        const float f1 = ok ? xv1[it] : 0.f;
        const int v = (int)(unsigned short)f2bf(f0) |
                      ((int)(unsigned short)f2bf(f1) << 16);
        ((int*)&xs[r][q + 1][0])[cp] = v;
    }
    if (tid < 96) {
        const int side = tid & 1;
        const int hrc  = tid >> 1;
        const int hcp  = hrc & 15;
        const int hr   = hrc >> 4;
        const int hrow = h + hr - 1;
        const int hwx  = wseg - 1 + side * 129;
        const bool hok = ((unsigned)hrow < (unsigned)H_) &&
                         ((unsigned)hwx  < (unsigned)W_);
        const float f0 = hok ? hv0 : 0.f;
        const float f1 = hok ? hv1 : 0.f;
        const int v = (int)(unsigned short)f2bf(f0) |
                      ((int)(unsigned short)f2bf(f1) << 16);
        ((int*)&xs[hr][side * 129][0])[hcp] = v;
    }
    {
        const int r0   = tid / 130;
        const int q0   = tid - r0 * 130;
        const bool ok0 = ((unsigned)(h + r0 - 1) < (unsigned)H_) &&
                         ((unsigned)(wseg - 1 + q0) < (unsigned)W_);
        dsh[r0][q0] = ok0 ? dv0 : 0.f;
        const int k1 = tid + 256;
        if (k1 < 390) {
            const int r1   = k1 / 130;
            const int q1   = k1 - r1 * 130;
            const bool ok1 = ((unsigned)(h + r1 - 1) < (unsigned)H_) &&
                             ((unsigned)(wseg - 1 + q1) < (unsigned)W_);
            dsh[r1][q1] = ok1 ? dv1 : 0.f;
        }
    }
    __syncthreads();

    // ================= compute: 2 subtiles per wave =================
    const int lane = tid & 63;
    const int warp = tid >> 6;
    const int n    = lane & 15;
    const int cg   = (lane >> 4) * 8;
    const int pl0  = warp * 32 + n + 1;
    const int pl1  = pl0 + 16;
    const int wp0  = wseg + warp * 32 + n;
    const int wp1  = wp0 + 16;

    const float dc0 = dsh[1][pl0];
    const float dc1 = dsh[1][pl1];

    float s0[KTAPS], s1[KTAPS];
#pragma unroll
    for (int ij = 0; ij < KTAPS; ++ij) {
        const int di = ij / 3 - 1;
        const int dj = ij % 3 - 1;
        const bool okh = ((unsigned)(h + di) < (unsigned)H_);
        const bool ok0 = okh && ((unsigned)(wp0 + dj) < (unsigned)W_);
        const bool ok1 = okh && ((unsigned)(wp1 + dj) < (unsigned)W_);
        s0[ij] = ok0 ? __expf(-ALPHA_F * fabsf(dc0 - dsh[1 + di][pl0 + dj])) : 0.f;
        s1[ij] = ok1 ? __expf(-ALPHA_F * fabsf(dc1 - dsh[1 + di][pl1 + dj])) : 0.f;
    }

    const bf16x8* wfv = (const bf16x8*)wf;
    f32x4 a00 = {0.f,0.f,0.f,0.f}, a01 = {0.f,0.f,0.f,0.f};
    f32x4 a10 = {0.f,0.f,0.f,0.f}, a11 = {0.f,0.f,0.f,0.f};
    const f32x4 z = {0.f, 0.f, 0.f, 0.f};
#pragma unroll
    for (int ij = 0; ij < KTAPS; ++ij) {
        const int di = ij / 3 - 1;
        const int dj = ij % 3 - 1;
        const bf16x8 wa0 = wfv[(ij * 2 + 0) * 64 + lane];
        const bf16x8 wa1 = wfv[(ij * 2 + 1) * 64 + lane];
        const bf16x8 b0  = *(const bf16x8*)&xs[1 + di][pl0 + dj][cg];
        const bf16x8 b1  = *(const bf16x8*)&xs[1 + di][pl1 + dj][cg];
        const f32x4 t0 = __builtin_amdgcn_mfma_f32_16x16x32_bf16(wa0, b0, z, 0, 0, 0);
        const f32x4 t1 = __builtin_amdgcn_mfma_f32_16x16x32_bf16(wa1, b0, z, 0, 0, 0);
        const f32x4 t2 = __builtin_amdgcn_mfma_f32_16x16x32_bf16(wa0, b1, z, 0, 0, 0);
        const f32x4 t3 = __builtin_amdgcn_mfma_f32_16x16x32_bf16(wa1, b1, z, 0, 0, 0);
#pragma unroll
        for (int j = 0; j < 4; ++j) {
            a00[j] = fmaf(s0[ij], t0[j], a00[j]);
            a01[j] = fmaf(s0[ij], t1[j], a01[j]);
            a10[j] = fmaf(s1[ij], t2[j], a10[j]);
            a11[j] = fmaf(s1[ij], t3[j], a11[j]);
        }
    }

    // ---- epilogue: strided stores (proven fast in R7 abl), nontemporal ----
    const int orow = (lane >> 4) * 4;
    float* ob0 = out + (size_t)b * COUT * HW + h * W_ + wp0;
    float* ob1 = out + (size_t)b * COUT * HW + h * W_ + wp1;
#pragma unroll
    for (int j = 0; j < 4; ++j) {
        __builtin_nontemporal_store(a00[j], ob0 + (size_t)(orow + j) * HW);
        __builtin_nontemporal_store(a01[j], ob0 + (size_t)(orow + j + 16) * HW);
        __builtin_nontemporal_store(a10[j], ob1 + (size_t)(orow + j) * HW);
        __builtin_nontemporal_store(a11[j], ob1 + (size_t)(orow + j + 16) * HW);
    }
}

// ---------- fp32 fallback (R1 kernel) ----------
__global__ __launch_bounds__(256)
void dconv_fallback(const float* __restrict__ x,
                    const float* __restrict__ depth,
                    const float* __restrict__ wgt,
                    float* __restrict__ out) {
    const int w  = threadIdx.x;
    const int bh = blockIdx.x;
    const int b  = bh >> 8;
    const int h  = bh & 255;

    const float* dplane = depth + (size_t)b * HW;
    const float  dc     = dplane[h * W_ + w];

    float acc[COUT];
#pragma unroll
    for (int o = 0; o < COUT; ++o) acc[o] = 0.f;

    const float* xb = x + (size_t)b * CIN * HW;

    for (int i = 0; i < 3; ++i) {
        const int  hh  = h + i - 1;
        const bool okh = ((unsigned)hh < (unsigned)H_);
        for (int j = 0; j < 3; ++j) {
            const int  ww = w + j - 1;
            const bool ok = okh && ((unsigned)ww < (unsigned)W_);
            const int  ij = i * 3 + j;
            const float dpv = ok ? dplane[hh * W_ + ww] : 0.f;
            const float sv  = __expf(-ALPHA_F * fabsf(dc - dpv));
            const int base = hh * W_ + ww;
#pragma unroll
            for (int c = 0; c < CIN; ++c) {
                const float v = (ok ? xb[c * HW + base] : 0.f) * sv;
#pragma unroll
                for (int o = 0; o < COUT; ++o) {
                    acc[o] = fmaf(v, wgt[(o * CIN + c) * KTAPS + ij], acc[o]);
                }
            }
        }
    }

    float* ob = out + ((size_t)b * COUT * H_ + h) * W_ + w;
#pragma unroll
    for (int o = 0; o < COUT; ++o) ob[o * HW] = acc[o];
}

extern "C" void kernel_launch(void* const* d_in, const int* in_sizes, int n_in,
                              void* d_out, int out_size, void* d_ws, size_t ws_size,
                              hipStream_t stream) {
    const float* x     = (const float*)d_in[0];
    const float* depth = (const float*)d_in[1];
    const float* wgt   = (const float*)d_in[2];
    float*       out   = (float*)d_out;

    const size_t wf_bytes = (size_t)(KTAPS * 2 * 64 * 8) * sizeof(short); // 18 KB

    if (ws_size >= wf_bytes) {
        short* wf = (short*)d_ws;
        prep_wfrag<<<(KTAPS * 2 * 64 * 8 + 255) / 256, 256, 0, stream>>>(wgt, wf);
        dconv_fused4<<<2048, 256, 0, stream>>>(x, depth, wf, out);
    } else {
        dconv_fallback<<<B_ * H_, 256, 0, stream>>>(x, depth, wgt, out);
    }
}